// Round 4
// baseline (120.752 us; speedup 1.0000x reference)
//
#include <hip/hip_runtime.h>

// SSIM, N=32 images 512x512 fp32, 11x11 Gaussian (separable via rank-1
// window), zero pad, scalar mean output.
//
// R13: R12's barrier-free wave-private structure + PIPELINE DISTANCE.
// R12 post-mortem (62us, VALUBusy 33%): zero barriers but every iteration
// serialized on its own LDS round-trip -- ds_write(row i) -> lgkm ->
// ds_read(row i) -> lgkm -> conv, ~240cy exposed per iteration. Producer
// and consumer were the same wave in the SAME iteration.
// Fix: 3-slot wave-private LDS ring gives the round-trip a full iteration
// of slack on each side:
//   iter i: read slot i%3 (row i, written at iter i-2)
//           write slot (i+2)%3 (row i+2, loaded at iter i-1)
//           load row i+3 -> pending regs
//           conv row i; vertical+epilogue
// Static-index discipline (R10 lesson: VGPR): vertical ring modulus 11->12
// (one pad slot), ITERS=36=3x12, inner unroll-12 makes %12 and %3 indices
// compile-time (12%3==0), outer loop stays `#pragma unroll 1`.
// RROWS 23->26 (ITERS exact 36): grid (20,32)=640. Row-iters/image 720 vs
// R12's 759 -- iso-work, delta attributable to the schedule.
// Evidence notes: 88-float ring lives in AGPRs (R12 VGPR_Count=64), unified
// budget ~160 -> 3 waves/SIMD. LDS pipe (8 b128/iter ~96cy) and VALU
// (~410cy/iter) are separate pipes; floor ~16-18us at 2.5 waves/SIMD.
// R8+ kept: packed fp32 (v_pk_*) on (s,d)=(x+y,x-y), M=2 cols/thread,
// 7x ds_read_b128 horizontal window, register vertical ring, same epilogue.

typedef float v2f __attribute__((ext_vector_type(2)));
typedef float v4f __attribute__((ext_vector_type(4)));

#define IMG_H 512
#define IMG_W 512
#define NIMG  32
#define NT    256
#define RROWS 26
#define NCHX  20             // ceil(512/26)
#define ITERS 36             // RROWS+10 = 3 x 12 exactly
// per-wave LDS slot: idx 0..139 hold (s,d) of cols C0-6 .. C0+133
// (idx i <-> col C0-6+i). 140 used, pad stride to 144 v2f (1152 B).
#define SEGW  144

#define C1F  1.0e-4f
#define C2F  9.0e-4f
#define EPSF 1.0e-8f

static __device__ __forceinline__ v2f pkfma(float s, v2f a, v2f b) {
    v2f sv = {s, s};
    return __builtin_elementwise_fma(sv, a, b);   // -> v_pk_fma_f32
}

__global__ __launch_bounds__(NT) void ssim_kernel(
    const float* __restrict__ xg, const float* __restrict__ yg,
    const float* __restrict__ wg, float* __restrict__ out)
{
    const int t    = threadIdx.x;       // 0..255
    const int lane = t & 63;
    const int wv   = t >> 6;            // wave id 0..3 -> col segment
    const int chnk = blockIdx.x;        // 0..19
    const int img  = blockIdx.y;        // 0..31
    const int r0   = chnk * RROWS;
    const int C0   = 128 * wv;          // segment col base
    const int cown = C0 + 2 * lane;     // owned cols cown, cown+1
    const int c0l  = 2 * lane;          // local LDS read base (idx units)

    const float* xb = xg + (size_t)img * (IMG_H * IMG_W);
    const float* yb = yg + (size_t)img * (IMG_H * IMG_W);

    __shared__ alignas(16) v2f seg[4][3][SEGW];   // 4 waves x 3 slots, 13.8KB
    __shared__ float wredS[4];

    // 1D taps = row sums of normalized 2D window -> SGPRs via readfirstlane.
    float rs = 0.f;
    if (lane < 11) {
        #pragma unroll
        for (int j = 0; j < 11; ++j) rs += wg[lane * 11 + j];
    }
    float g[11];
    #pragma unroll
    for (int k = 0; k < 11; ++k) {
        int gi = __shfl(__float_as_int(rs), k, 64);
        g[k] = __int_as_float(__builtin_amdgcn_readfirstlane(gi));
    }

    const v2f z2 = {0.f, 0.f};

    // halo duty: lanes 0..2 left (cols C0-6+2*lane), lanes 61..63 right
    // (cols C0+128+2*(lane-61)). Out-of-image -> z2 via range guard.
    const bool isH = (lane < 3) || (lane >= 61);
    const int  hcol = (lane < 3) ? (C0 - 6 + 2 * lane)
                                 : (C0 + 128 + 2 * (lane - 61));
    const int  hidx = (lane < 3) ? (2 * lane) : (134 + 2 * (lane - 61));

    v2f px, py, hx, hy;     // pending-row registers (row to be staged next+1)

#define LOADROW(ROW) do {                                                  \
        const int r_ = (ROW);                                              \
        px = z2; py = z2; hx = z2; hy = z2;                                \
        if ((unsigned)r_ < IMG_H) {                                        \
            const float* xr = xb + (size_t)r_ * IMG_W;                     \
            const float* yr = yb + (size_t)r_ * IMG_W;                     \
            px = *(const v2f*)(xr + cown);                                 \
            py = *(const v2f*)(yr + cown);                                 \
            if (isH && (unsigned)hcol < IMG_W) {                           \
                hx = *(const v2f*)(xr + hcol);                             \
                hy = *(const v2f*)(yr + hcol);                             \
            }                                                              \
        }                                                                  \
    } while (0)

#define WRITESLOT(SL) do {                                                 \
        const v2f sv_ = px + py;        /* v_pk_add_f32 */                 \
        const v2f dv_ = px - py;                                           \
        v4f st_ = {sv_.x, dv_.x, sv_.y, dv_.y};                            \
        *(v4f*)&seg[wv][(SL)][6 + c0l] = st_;                              \
        if (isH) {                                                         \
            const v2f hs_ = hx + hy;                                       \
            const v2f hd_ = hx - hy;                                       \
            v4f ht_ = {hs_.x, hd_.x, hs_.y, hd_.y};                        \
            *(v4f*)&seg[wv][(SL)][hidx] = ht_;                             \
        }                                                                  \
    } while (0)

    // prologue: rows 0,1 (r0-5, r0-4) staged to slots 0,1; row 2 pending.
    LOADROW(r0 - 5);
    WRITESLOT(0);
    LOADROW(r0 - 4);
    WRITESLOT(1);
    LOADROW(r0 - 3);

    // vertical register rings, 12 slots (slot 11+1 pad for static %12)
    v2f rSD[12][2], rQ[12][2];

    float acc = 0.f;

    #pragma unroll 1
    for (int base = 0; base < ITERS; base += 12) {
        #pragma unroll
        for (int s = 0; s < 12; ++s) {
            const int i = base + s;     // streamed-row index; i%12==s,
                                        // i%3==s%3 (base multiple of 12)

            // ---- read row i's window: slot written at iter i-2 ----
            v4f w4r[7];
            #pragma unroll
            for (int m = 0; m < 7; ++m)
                w4r[m] = *(const v4f*)&seg[wv][s % 3][c0l + 2 * m];

            // ---- stage row i+2 (loaded at iter i-1) ----
            WRITESLOT((s + 2) % 3);

            // ---- issue loads for row i+3 (staged at iter i+1) ----
            LOADROW(r0 - 5 + i + 3);

            // ---- horizontal conv of row i from w4r ----
            // window element j (0..13) at idx c0l+j (col cown-6+j)
            v2f hA = z2, hB = z2, qA = z2, qB = z2;
            #pragma unroll
            for (int m = 0; m < 7; ++m) {
                const v4f w4 = w4r[m];
                const v2f e0 = {w4.x, w4.y};   // j = 2m
                const v2f e1 = {w4.z, w4.w};   // j = 2m+1
                {
                    const int j = 2 * m;
                    if (j >= 1) {
                        const v2f f0 = e0 * e0;          // v_pk_mul_f32
                        if (j <= 11) {
                            hA = pkfma(g[j - 1], e0, hA);
                            qA = pkfma(g[j - 1], f0, qA);
                        }
                        if (j >= 2) {
                            hB = pkfma(g[j - 2], e0, hB);
                            qB = pkfma(g[j - 2], f0, qB);
                        }
                    }
                }
                {
                    const int j = 2 * m + 1;
                    if (j <= 12) {
                        const v2f f1 = e1 * e1;
                        if (j <= 11) {
                            hA = pkfma(g[j - 1], e1, hA);
                            qA = pkfma(g[j - 1], f1, qA);
                        }
                        if (j >= 2) {
                            hB = pkfma(g[j - 2], e1, hB);
                            qB = pkfma(g[j - 2], f1, qB);
                        }
                    }
                }
            }
            rSD[s][0] = hA; rSD[s][1] = hB;
            rQ[s][0]  = qA; rQ[s][1]  = qB;

            // ---- vertical conv + SSIM epilogue (output row r0 + i - 10) ----
            if (i >= 10) {                       // wave-uniform
                const int orow = r0 + i - 10;
                if (orow < IMG_H) {              // wave-uniform tail guard
                    #pragma unroll
                    for (int cc = 0; cc < 2; ++cc) {
                        v2f mSD = z2, mQ = z2;
                        #pragma unroll
                        for (int j = 0; j < 11; ++j) {
                            // input rows i-10+j -> ring slot (i+2+j)%12
                            const int sl = (s + 2 + j) % 12;   // static
                            mSD = pkfma(g[j], rSD[sl][cc], mSD);
                            mQ  = pkfma(g[j], rQ[sl][cc],  mQ);
                        }
                        const v2f t2 = mSD * mSD;      // (mS^2, mD^2)
                        const float a    = 0.5f  * (t2.x + t2.y); // mx2+my2
                        const float muxy = 0.25f * (t2.x - t2.y); // mx*my
                        const float ep   = 0.5f  * (mQ.x + mQ.y); // Ex2+Ey2
                        const float eq   = 0.25f * (mQ.x - mQ.y); // Exy
                        const float sxy  = eq - muxy;
                        const float ssum = ep - a;
                        const float num  = fmaf(2.f, muxy, C1F) * fmaf(2.f, sxy, C2F);
                        const float den  = (a + C1F) * (ssum + C2F);
                        float v = num * __builtin_amdgcn_rcpf(den + EPSF);
                        acc += fminf(fmaxf(v, 0.f), 1.f);
                    }
                }
            }
        }
    }

    // block reduction: wave shuffle, 4 slots in LDS, one atomic per block.
    // (The only __syncthreads in the kernel.)
    #pragma unroll
    for (int off = 32; off > 0; off >>= 1)
        acc += __shfl_down(acc, off, 64);
    if (lane == 0) wredS[wv] = acc;
    __syncthreads();
    if (t == 0) {
        const float tot = (wredS[0] + wredS[1]) + (wredS[2] + wredS[3]);
        atomicAdd(out, tot * (1.0f / (float)((size_t)NIMG * IMG_H * IMG_W)));
    }
}

extern "C" void kernel_launch(void* const* d_in, const int* in_sizes, int n_in,
                              void* d_out, int out_size, void* d_ws, size_t ws_size,
                              hipStream_t stream) {
    const float* x = (const float*)d_in[0];
    const float* y = (const float*)d_in[1];
    const float* w = (const float*)d_in[2];
    float* out = (float*)d_out;

    // d_out is re-poisoned to 0xAA before every timed launch; zero it first.
    hipMemsetAsync(out, 0, sizeof(float), stream);

    dim3 grid(NCHX, NIMG);    // (20, 32) = 640 blocks
    ssim_kernel<<<grid, dim3(NT), 0, stream>>>(x, y, w, out);
}